// Round 1
// baseline (2153.684 us; speedup 1.0000x reference)
//
#include <hip/hip_runtime.h>
#include <hip/hip_bf16.h>
#include <cstdint>

// Sizes (fixed by the problem)
#define TT 1024
#define BB 64
#define DD 1024
#define HH 30
#define G4 120   // 4*H
#define GP 128   // padded gate dim

// ---------------------------------------------------------------------------
// fast activations (accuracy ~1-2 ulp, far under the 3.8e-3 threshold)
__device__ __forceinline__ float frcp(float x) { return __builtin_amdgcn_rcpf(x); }
__device__ __forceinline__ float fsig(float x) { return frcp(1.0f + __expf(-x)); }
__device__ __forceinline__ float ftanhf(float x) {
    // 2*sigmoid(2x)-1 : no inf/inf NaN for large |x|
    return 2.0f * frcp(1.0f + __expf(-2.0f * x)) - 1.0f;
}

// ---------------------------------------------------------------------------
// Prep: Wt0[k][g] = W_ih0[g][k] (g<120, else 0), bias0[g] = b_ih0[g]+b_hh0[g]
__global__ void prep_kernel(const float* __restrict__ Wih0,
                            const float* __restrict__ bih0,
                            const float* __restrict__ bhh0,
                            float* __restrict__ Wt0, float* __restrict__ bias0) {
    int idx = blockIdx.x * 256 + threadIdx.x;      // 0 .. 1024*128-1
    int k = idx >> 7, g = idx & 127;
    Wt0[idx] = (g < G4) ? Wih0[g * DD + k] : 0.0f;
    if (idx < GP) bias0[idx] = (idx < G4) ? (bih0[idx] + bhh0[idx]) : 0.0f;
}

// ---------------------------------------------------------------------------
// GEMM: xg0[r][g] = dot(x[r][:], Wih0[g][:]) + bias0[g]
//   block: 256 threads, 32 rows x 128 cols, K-chunks of 64
__global__ __launch_bounds__(256) void gemm_xg_kernel(
    const float* __restrict__ x, const float* __restrict__ Wt0,
    const float* __restrict__ bias0, float* __restrict__ xg0) {
    const int tid = threadIdx.x;
    const int r0 = blockIdx.x * 32;
    __shared__ __align__(16) float xs_t[64][36];   // [kk][r], pad 36 for alignment
    __shared__ __align__(16) float wt_s[64 * 128]; // [kk][g]

    const int g = tid & 127;       // col
    const int rh = tid >> 7;       // row half (0/1)
    const int r = tid >> 3;        // staging row 0..31
    const int kq = tid & 7;        // staging k-octet

    float acc[16];
#pragma unroll
    for (int i = 0; i < 16; ++i) acc[i] = 0.0f;

    for (int kc = 0; kc < DD / 64; ++kc) {
        const int k0 = kc * 64;
        // issue global loads early (hide latency across the barrier)
        const float* xrow = x + (size_t)(r0 + r) * DD + k0 + kq * 8;
        float4 xa = *(const float4*)(xrow);
        float4 xb = *(const float4*)(xrow + 4);
        float4 wv[8];
        const float4* wsrc = (const float4*)(Wt0 + (size_t)k0 * 128);
#pragma unroll
        for (int j = 0; j < 8; ++j) wv[j] = wsrc[j * 256 + tid];

        __syncthreads();  // previous chunk's compute done before overwrite
        // transposed x store
        xs_t[kq * 8 + 0][r] = xa.x; xs_t[kq * 8 + 1][r] = xa.y;
        xs_t[kq * 8 + 2][r] = xa.z; xs_t[kq * 8 + 3][r] = xa.w;
        xs_t[kq * 8 + 4][r] = xb.x; xs_t[kq * 8 + 5][r] = xb.y;
        xs_t[kq * 8 + 6][r] = xb.z; xs_t[kq * 8 + 7][r] = xb.w;
#pragma unroll
        for (int j = 0; j < 8; ++j) ((float4*)wt_s)[j * 256 + tid] = wv[j];
        __syncthreads();

#pragma unroll 8
        for (int kk = 0; kk < 64; ++kk) {
            float w = wt_s[kk * 128 + g];
            const float4* xr = (const float4*)&xs_t[kk][rh * 16];
            float4 x0 = xr[0], x1 = xr[1], x2 = xr[2], x3 = xr[3];
            acc[0]  = fmaf(x0.x, w, acc[0]);  acc[1]  = fmaf(x0.y, w, acc[1]);
            acc[2]  = fmaf(x0.z, w, acc[2]);  acc[3]  = fmaf(x0.w, w, acc[3]);
            acc[4]  = fmaf(x1.x, w, acc[4]);  acc[5]  = fmaf(x1.y, w, acc[5]);
            acc[6]  = fmaf(x1.z, w, acc[6]);  acc[7]  = fmaf(x1.w, w, acc[7]);
            acc[8]  = fmaf(x2.x, w, acc[8]);  acc[9]  = fmaf(x2.y, w, acc[9]);
            acc[10] = fmaf(x2.z, w, acc[10]); acc[11] = fmaf(x2.w, w, acc[11]);
            acc[12] = fmaf(x3.x, w, acc[12]); acc[13] = fmaf(x3.y, w, acc[13]);
            acc[14] = fmaf(x3.z, w, acc[14]); acc[15] = fmaf(x3.w, w, acc[15]);
        }
    }

    if (g < G4) {
        float bb = bias0[g];
        const int rbase = r0 + rh * 16;
#pragma unroll
        for (int i = 0; i < 16; ++i)
            xg0[(size_t)(rbase + i) * G4 + g] = acc[i] + bb;
    }
}

// ---------------------------------------------------------------------------
// Fused 2-layer recurrence + output head. One block per batch element.
// 128 threads: thread g (<120) owns gate row g of both layers; threads <30
// own hidden unit u for the c/h updates.
__global__ __launch_bounds__(128, 1) void lstm_rec_kernel(
    const float* __restrict__ xg0,
    const float* __restrict__ Whh0, const float* __restrict__ Wih1,
    const float* __restrict__ Whh1, const float* __restrict__ bih1,
    const float* __restrict__ bhh1, const float* __restrict__ Wout,
    const float* __restrict__ bout, float* __restrict__ out) {
    const int tid = threadIdx.x;
    const int b = blockIdx.x;

    __shared__ __align__(16) float h1s[32];
    __shared__ __align__(16) float h2s[32];
    __shared__ float g0s[G4];
    __shared__ float g1s[G4];

    // recurrent weights in registers (rows of Whh0 / Wih1 / Whh1), zero-padded
    float w0[32], wi1[32], w1[32];
#pragma unroll
    for (int j = 0; j < 32; ++j) {
        bool v = (tid < G4) && (j < HH);
        w0[j]  = v ? Whh0[tid * HH + j] : 0.0f;
        wi1[j] = v ? Wih1[tid * HH + j] : 0.0f;
        w1[j]  = v ? Whh1[tid * HH + j] : 0.0f;
    }
    float bias1 = (tid < G4) ? (bih1[tid] + bhh1[tid]) : 0.0f;
    float wo = (tid < HH) ? Wout[tid] : 0.0f;
    float bo = bout[0];
    float c1 = 0.0f, c2 = 0.0f;

    if (tid < 32) { h1s[tid] = 0.0f; h2s[tid] = 0.0f; }
    __syncthreads();

    float xw = (tid < G4) ? xg0[(size_t)b * G4 + tid] : 0.0f;  // t = 0

    for (int t = 0; t < TT; ++t) {
        // prefetch next step's xg row
        int tn = (t + 1 < TT) ? (t + 1) : t;
        float xn = (tid < G4) ? xg0[((size_t)tn * BB + b) * G4 + tid] : 0.0f;

        // ---- P0: layer-0 gates = xw + Whh0[g] . h1 ----
        float a0 = xw;
        {
            const float4* hp = (const float4*)h1s;
            float s0 = 0, s1 = 0, s2 = 0, s3 = 0;
#pragma unroll
            for (int q = 0; q < 8; ++q) {
                float4 h4 = hp[q];
                s0 = fmaf(w0[q * 4 + 0], h4.x, s0);
                s1 = fmaf(w0[q * 4 + 1], h4.y, s1);
                s2 = fmaf(w0[q * 4 + 2], h4.z, s2);
                s3 = fmaf(w0[q * 4 + 3], h4.w, s3);
            }
            a0 += (s0 + s1) + (s2 + s3);
        }
        if (tid < G4) g0s[tid] = a0;
        __syncthreads();

        // ---- P1: layer-0 cell/hidden update ----
        if (tid < HH) {
            float ig = fsig(g0s[tid]);
            float fg = fsig(g0s[HH + tid]);
            float gg = ftanhf(g0s[2 * HH + tid]);
            float og = fsig(g0s[3 * HH + tid]);
            c1 = fg * c1 + ig * gg;
            h1s[tid] = og * ftanhf(c1);
        }
        __syncthreads();

        // ---- P2: layer-1 gates = bias1 + Wih1[g].h1 + Whh1[g].h2 ----
        float a1 = bias1;
        {
            const float4* hp1 = (const float4*)h1s;
            const float4* hp2 = (const float4*)h2s;
            float s0 = 0, s1 = 0, s2 = 0, s3 = 0;
#pragma unroll
            for (int q = 0; q < 8; ++q) {
                float4 h4 = hp1[q];
                float4 e4 = hp2[q];
                s0 = fmaf(wi1[q * 4 + 0], h4.x, s0);
                s1 = fmaf(wi1[q * 4 + 1], h4.y, s1);
                s2 = fmaf(wi1[q * 4 + 2], h4.z, s2);
                s3 = fmaf(wi1[q * 4 + 3], h4.w, s3);
                s0 = fmaf(w1[q * 4 + 0], e4.x, s0);
                s1 = fmaf(w1[q * 4 + 1], e4.y, s1);
                s2 = fmaf(w1[q * 4 + 2], e4.z, s2);
                s3 = fmaf(w1[q * 4 + 3], e4.w, s3);
            }
            a1 += (s0 + s1) + (s2 + s3);
        }
        if (tid < G4) g1s[tid] = a1;
        __syncthreads();

        // ---- P3: layer-1 update + output head ----
        float p = 0.0f;
        if (tid < HH) {
            float ig = fsig(g1s[tid]);
            float fg = fsig(g1s[HH + tid]);
            float gg = ftanhf(g1s[2 * HH + tid]);
            float og = fsig(g1s[3 * HH + tid]);
            c2 = fg * c2 + ig * gg;
            float h2 = og * ftanhf(c2);
            h2s[tid] = h2;
            p = h2 * wo;
        }
        // reduce p over lanes 0..31 (units live in wave 0)
        p += __shfl_xor(p, 16, 32);
        p += __shfl_xor(p, 8, 32);
        p += __shfl_xor(p, 4, 32);
        p += __shfl_xor(p, 2, 32);
        p += __shfl_xor(p, 1, 32);
        if (tid == 0) out[t * BB + b] = p + bo;
        __syncthreads();

        xw = xn;
    }
}

// ---------------------------------------------------------------------------
extern "C" void kernel_launch(void* const* d_in, const int* in_sizes, int n_in,
                              void* d_out, int out_size, void* d_ws, size_t ws_size,
                              hipStream_t stream) {
    const float* x    = (const float*)d_in[0];
    const float* Wih0 = (const float*)d_in[1];
    const float* Whh0 = (const float*)d_in[2];
    const float* bih0 = (const float*)d_in[3];
    const float* bhh0 = (const float*)d_in[4];
    const float* Wih1 = (const float*)d_in[5];
    const float* Whh1 = (const float*)d_in[6];
    const float* bih1 = (const float*)d_in[7];
    const float* bhh1 = (const float*)d_in[8];
    const float* Wout = (const float*)d_in[9];
    const float* bout = (const float*)d_in[10];
    float* out = (float*)d_out;

    char* ws = (char*)d_ws;
    float* Wt0   = (float*)ws;                      // 1024*128*4 = 512 KB
    float* bias0 = (float*)(ws + 512 * 1024);       // 512 B
    float* xg0   = (float*)(ws + 1024 * 1024);      // 65536*120*4 = 31.5 MB

    prep_kernel<<<512, 256, 0, stream>>>(Wih0, bih0, bhh0, Wt0, bias0);
    gemm_xg_kernel<<<(TT * BB) / 32, 256, 0, stream>>>(x, Wt0, bias0, xg0);
    lstm_rec_kernel<<<BB, 128, 0, stream>>>(xg0, Whh0, Wih1, Whh1, bih1, bhh1,
                                            Wout, bout, out);
}

// Round 2
// 1394.111 us; speedup vs baseline: 1.5448x; 1.5448x over previous
//
#include <hip/hip_runtime.h>
#include <hip/hip_bf16.h>
#include <cstdint>

#define TT 1024
#define BB 64
#define DD 1024
#define HH 30
#define G4 120
#define KC 16

// ---------------------------------------------------------------------------
__device__ __forceinline__ float frcp(float x) { return __builtin_amdgcn_rcpf(x); }
__device__ __forceinline__ float fsig(float x) { return frcp(1.0f + __expf(-x)); }
__device__ __forceinline__ float ftan(float x) {
    return 2.0f * frcp(1.0f + __expf(-2.0f * x)) - 1.0f;
}
__device__ __forceinline__ float bcast(float v, int l) {
    return __int_as_float(__builtin_amdgcn_readlane(__float_as_int(v), l));
}

// ---------------------------------------------------------------------------
// Prep: Wt0[k][g] = W_ih0[g][k] (g<120 else 0); bias0[g] = b_ih0[g]+b_hh0[g]
__global__ void prep_kernel(const float* __restrict__ Wih0,
                            const float* __restrict__ bih0,
                            const float* __restrict__ bhh0,
                            float* __restrict__ Wt0, float* __restrict__ bias0) {
    int idx = blockIdx.x * 256 + threadIdx.x;   // 0 .. 1024*128-1
    int k = idx >> 7, g = idx & 127;
    Wt0[idx] = (g < G4) ? Wih0[g * DD + k] : 0.0f;
    if (idx < 128) bias0[idx] = (idx < G4) ? (bih0[idx] + bhh0[idx]) : 0.0f;
}

// ---------------------------------------------------------------------------
// GEMM: xgp[row][lane][slot] = x[row][:] . Wih0[g][:] + bias0[g]  (permuted)
// block = 256 rows x 128 cols, 256 threads, thread tile 16 rows x 8 cols.
__global__ __launch_bounds__(256) void gemm_xg(
    const float* __restrict__ x, const float* __restrict__ Wt0,
    const float* __restrict__ bias0, float* __restrict__ xgp) {
    __shared__ __align__(16) float xs[KC][264];   // [k][row], padded
    __shared__ __align__(16) float ws[KC][132];   // [k][col], padded
    const int tid = threadIdx.x;
    const int r0 = blockIdx.x * 256;
    const int rg = tid >> 4;          // 0..15 -> rows rg*16..+15
    const int cg = tid & 15;          // 0..15 -> cols cg*8..+7

    // staging coords
    const int sr = tid >> 2;          // 0..63
    const int sk = (tid & 3) * 4;     // 0,4,8,12
    const int wk = tid >> 4;          // 0..15
    const int wc = (tid & 15) * 8;    // 0..120

    float acc[16][8];
#pragma unroll
    for (int i = 0; i < 16; ++i)
#pragma unroll
        for (int j = 0; j < 8; ++j) acc[i][j] = 0.0f;

    float4 px[4], pw[2];
    // preload chunk 0
#pragma unroll
    for (int p = 0; p < 4; ++p)
        px[p] = *(const float4*)&x[(size_t)(r0 + sr + p * 64) * DD + sk];
    pw[0] = *(const float4*)&Wt0[(size_t)wk * 128 + wc];
    pw[1] = *(const float4*)&Wt0[(size_t)wk * 128 + wc + 4];

    for (int kc = 0; kc < DD / KC; ++kc) {
        __syncthreads();   // previous chunk's compute done
#pragma unroll
        for (int p = 0; p < 4; ++p) {
            xs[sk + 0][sr + p * 64] = px[p].x;
            xs[sk + 1][sr + p * 64] = px[p].y;
            xs[sk + 2][sr + p * 64] = px[p].z;
            xs[sk + 3][sr + p * 64] = px[p].w;
        }
        *(float4*)&ws[wk][wc]     = pw[0];
        *(float4*)&ws[wk][wc + 4] = pw[1];
        __syncthreads();

        if (kc + 1 < DD / KC) {   // prefetch next chunk during compute
            const int k0 = (kc + 1) * KC;
#pragma unroll
            for (int p = 0; p < 4; ++p)
                px[p] = *(const float4*)&x[(size_t)(r0 + sr + p * 64) * DD + k0 + sk];
            pw[0] = *(const float4*)&Wt0[(size_t)(k0 + wk) * 128 + wc];
            pw[1] = *(const float4*)&Wt0[(size_t)(k0 + wk) * 128 + wc + 4];
        }

#pragma unroll
        for (int kk = 0; kk < KC; ++kk) {
            float xr[16], wr[8];
            const float4* xp = (const float4*)&xs[kk][rg * 16];
            float4 x0 = xp[0], x1 = xp[1], x2 = xp[2], x3 = xp[3];
            xr[0]=x0.x; xr[1]=x0.y; xr[2]=x0.z; xr[3]=x0.w;
            xr[4]=x1.x; xr[5]=x1.y; xr[6]=x1.z; xr[7]=x1.w;
            xr[8]=x2.x; xr[9]=x2.y; xr[10]=x2.z; xr[11]=x2.w;
            xr[12]=x3.x; xr[13]=x3.y; xr[14]=x3.z; xr[15]=x3.w;
            const float4* wp = (const float4*)&ws[kk][cg * 8];
            float4 w0 = wp[0], w1 = wp[1];
            wr[0]=w0.x; wr[1]=w0.y; wr[2]=w0.z; wr[3]=w0.w;
            wr[4]=w1.x; wr[5]=w1.y; wr[6]=w1.z; wr[7]=w1.w;
#pragma unroll
            for (int i = 0; i < 16; ++i)
#pragma unroll
                for (int j = 0; j < 8; ++j)
                    acc[i][j] = fmaf(xr[i], wr[j], acc[i][j]);
        }
    }

    // epilogue: permuted store. gate g -> lane/slot for the recurrence layout
#pragma unroll
    for (int j = 0; j < 8; ++j) {
        const int g = cg * 8 + j;
        if (g < G4) {
            const int gm = g % 60;
            const int lane = (gm < HH) ? gm : (32 + gm - HH);
            const int slot = g / 60;
            const float bb = bias0[g];
#pragma unroll
            for (int i = 0; i < 16; ++i) {
                const size_t row = r0 + rg * 16 + i;
                xgp[(row * 64 + lane) * 2 + slot] = acc[i][j] + bb;
            }
        }
    }
}

// ---------------------------------------------------------------------------
// Recurrence: one wave per batch element, no barriers, no LDS.
// lane l: u=l&31, half=l>>5. half0 owns gate rows (i_u, g_u), half1 (f_u, o_u).
__global__ __launch_bounds__(64, 1) void lstm_rec(
    const float* __restrict__ xgp,
    const float* __restrict__ Whh0, const float* __restrict__ Wih1,
    const float* __restrict__ Whh1, const float* __restrict__ bih1,
    const float* __restrict__ bhh1, float* __restrict__ h2buf) {
    const int l = threadIdx.x;
    const int b = blockIdx.x;
    const int u = l & 31;
    const int half = l >> 5;
    const bool act = (u < HH);
    const int rlo = half * HH + (act ? u : 0);
    const int rhi = 60 + rlo;

    float w0lo[HH], w0hi[HH], wi1lo[HH], wi1hi[HH], wh1lo[HH], wh1hi[HH];
#pragma unroll
    for (int j = 0; j < HH; ++j) {
        w0lo[j]  = act ? Whh0[rlo * HH + j] : 0.0f;
        w0hi[j]  = act ? Whh0[rhi * HH + j] : 0.0f;
        wi1lo[j] = act ? Wih1[rlo * HH + j] : 0.0f;
        wi1hi[j] = act ? Wih1[rhi * HH + j] : 0.0f;
        wh1lo[j] = act ? Whh1[rlo * HH + j] : 0.0f;
        wh1hi[j] = act ? Whh1[rhi * HH + j] : 0.0f;
    }
    const float b1lo = act ? (bih1[rlo] + bhh1[rlo]) : 0.0f;
    const float b1hi = act ? (bih1[rhi] + bhh1[rhi]) : 0.0f;

    float h1 = 0.0f, c1 = 0.0f, h2 = 0.0f, c2 = 0.0f;

    const float2* xgptr = (const float2*)xgp + (size_t)b * 64 + l;
    float2 xw = xgptr[0];

    for (int t = 0; t < TT; ++t) {
        float2 xn = xgptr[(size_t)(t + 1 < TT ? t + 1 : t) * (BB * 64)];

        // ---- layer-0 gates (2 partial chains per gate for ILP) ----
        float aloA = xw.x, aloB = 0.0f, ahiA = xw.y, ahiB = 0.0f;
#pragma unroll
        for (int j = 0; j < HH; j += 2) {
            float hja = bcast(h1, j);
            float hjb = bcast(h1, j + 1);
            aloA = fmaf(w0lo[j], hja, aloA);
            ahiA = fmaf(w0hi[j], hja, ahiA);
            if (j + 1 < HH) {
                aloB = fmaf(w0lo[j + 1], hjb, aloB);
                ahiB = fmaf(w0hi[j + 1], hjb, ahiB);
            }
        }
        float alo = aloA + aloB, ahi = ahiA + ahiB;

        float plo = __shfl_xor(alo, 32, 64);
        float phi = __shfl_xor(ahi, 32, 64);
        float ipre = half ? plo : alo;
        float fpre = half ? alo : plo;
        float gpre = half ? phi : ahi;
        float opre = half ? ahi : phi;
        c1 = fsig(fpre) * c1 + fsig(ipre) * ftan(gpre);
        h1 = fsig(opre) * ftan(c1);

        // ---- layer-1 gates ----
        float zloA = b1lo, zloB = 0.0f, zhiA = b1hi, zhiB = 0.0f;
#pragma unroll
        for (int j = 0; j < HH; j += 2) {
            float hja = bcast(h2, j);
            float hjb = bcast(h2, j + 1);
            zloA = fmaf(wh1lo[j], hja, zloA);
            zhiA = fmaf(wh1hi[j], hja, zhiA);
            if (j + 1 < HH) {
                zloB = fmaf(wh1lo[j + 1], hjb, zloB);
                zhiB = fmaf(wh1hi[j + 1], hjb, zhiB);
            }
        }
#pragma unroll
        for (int j = 0; j < HH; j += 2) {
            float hja = bcast(h1, j);
            float hjb = bcast(h1, j + 1);
            zloA = fmaf(wi1lo[j], hja, zloA);
            zhiA = fmaf(wi1hi[j], hja, zhiA);
            if (j + 1 < HH) {
                zloB = fmaf(wi1lo[j + 1], hjb, zloB);
                zhiB = fmaf(wi1hi[j + 1], hjb, zhiB);
            }
        }
        float zlo = zloA + zloB, zhi = zhiA + zhiB;

        plo = __shfl_xor(zlo, 32, 64);
        phi = __shfl_xor(zhi, 32, 64);
        ipre = half ? plo : zlo;
        fpre = half ? zlo : plo;
        gpre = half ? phi : zhi;
        opre = half ? zhi : phi;
        c2 = fsig(fpre) * c2 + fsig(ipre) * ftan(gpre);
        h2 = fsig(opre) * ftan(c2);

        if (l < HH) h2buf[((size_t)t * BB + b) * 32 + l] = h2;
        xw = xn;
    }
}

// ---------------------------------------------------------------------------
// Output projection: out[t,b] = h2buf[t,b,:] . Wout + bout
__global__ __launch_bounds__(256) void out_proj(
    const float* __restrict__ h2buf, const float* __restrict__ Wout,
    const float* __restrict__ bout, float* __restrict__ out) {
    __shared__ float wos[32];
    if (threadIdx.x < 32)
        wos[threadIdx.x] = (threadIdx.x < HH) ? Wout[threadIdx.x] : 0.0f;
    __syncthreads();
    const int idx = blockIdx.x * 256 + threadIdx.x;   // 0..65535
    const float4* hp = (const float4*)(h2buf + (size_t)idx * 32);
    float s0 = 0.f, s1 = 0.f;
#pragma unroll
    for (int q = 0; q < 8; ++q) {
        float4 h = hp[q];
        s0 = fmaf(h.x, wos[q * 4 + 0], s0);
        s1 = fmaf(h.y, wos[q * 4 + 1], s1);
        s0 = fmaf(h.z, wos[q * 4 + 2], s0);
        s1 = fmaf(h.w, wos[q * 4 + 3], s1);
    }
    out[idx] = s0 + s1 + bout[0];
}

// ---------------------------------------------------------------------------
extern "C" void kernel_launch(void* const* d_in, const int* in_sizes, int n_in,
                              void* d_out, int out_size, void* d_ws, size_t ws_size,
                              hipStream_t stream) {
    const float* x    = (const float*)d_in[0];
    const float* Wih0 = (const float*)d_in[1];
    const float* Whh0 = (const float*)d_in[2];
    const float* bih0 = (const float*)d_in[3];
    const float* bhh0 = (const float*)d_in[4];
    const float* Wih1 = (const float*)d_in[5];
    const float* Whh1 = (const float*)d_in[6];
    const float* bih1 = (const float*)d_in[7];
    const float* bhh1 = (const float*)d_in[8];
    const float* Wout = (const float*)d_in[9];
    const float* bout = (const float*)d_in[10];
    float* out = (float*)d_out;

    char* ws = (char*)d_ws;
    float* Wt0   = (float*)ws;                             // 512 KB
    float* bias0 = (float*)(ws + 512 * 1024);              // 512 B
    float* xgp   = (float*)(ws + 1024 * 1024);             // 1024*64*64*2*4 = 33.55 MB
    float* h2buf = (float*)(ws + 36 * 1024 * 1024);        // 1024*64*32*4  = 8.39 MB

    prep_kernel<<<512, 256, 0, stream>>>(Wih0, bih0, bhh0, Wt0, bias0);
    gemm_xg<<<256, 256, 0, stream>>>(x, Wt0, bias0, xgp);
    lstm_rec<<<BB, 64, 0, stream>>>(xgp, Whh0, Wih1, Whh1, bih1, bhh1, h2buf);
    out_proj<<<256, 256, 0, stream>>>(h2buf, Wout, bout, out);
}

// Round 3
// 1205.668 us; speedup vs baseline: 1.7863x; 1.1563x over previous
//
#include <hip/hip_runtime.h>
#include <hip/hip_bf16.h>
#include <cstdint>

#define TT 1024
#define BB 64
#define DD 1024
#define HH 30
#define G4 120
#define KC 16

// ---------------------------------------------------------------------------
__device__ __forceinline__ float frcp(float x) { return __builtin_amdgcn_rcpf(x); }
__device__ __forceinline__ float fsig(float x) { return frcp(1.0f + __expf(-x)); }
__device__ __forceinline__ float ftan(float x) {
    return 2.0f * frcp(1.0f + __expf(-2.0f * x)) - 1.0f;
}
__device__ __forceinline__ float bcast(float v, int l) {
    return __int_as_float(__builtin_amdgcn_readlane(__float_as_int(v), l));
}

// ---------------------------------------------------------------------------
// Prep: Wt0[k][g] = W_ih0[g][k] (g<120 else 0); bias0[g] = b_ih0[g]+b_hh0[g]
__global__ void prep_kernel(const float* __restrict__ Wih0,
                            const float* __restrict__ bih0,
                            const float* __restrict__ bhh0,
                            float* __restrict__ Wt0, float* __restrict__ bias0) {
    int idx = blockIdx.x * 256 + threadIdx.x;   // 0 .. 1024*128-1
    int k = idx >> 7, g = idx & 127;
    Wt0[idx] = (g < G4) ? Wih0[g * DD + k] : 0.0f;
    if (idx < 128) bias0[idx] = (idx < G4) ? (bih0[idx] + bhh0[idx]) : 0.0f;
}

// ---------------------------------------------------------------------------
// GEMM: 128 rows x 128 cols per block, 256 threads, 8x8 thread tile.
__global__ __launch_bounds__(256) void gemm_xg(
    const float* __restrict__ x, const float* __restrict__ Wt0,
    const float* __restrict__ bias0, float* __restrict__ xgp) {
    __shared__ __align__(16) float xs[KC][136];   // [k][row]
    __shared__ __align__(16) float ws[KC][132];   // [k][col]
    const int tid = threadIdx.x;
    const int r0 = blockIdx.x * 128;
    const int rg = tid >> 4;          // 0..15 -> rows rg*8..+7
    const int cg = tid & 15;          // 0..15 -> cols cg*8..+7

    // staging coords
    const int sr = tid >> 1;          // 0..127 (x row)
    const int sk = (tid & 1) * 8;     // 0 or 8 (x k-offset)
    const int ka = tid >> 5;          // 0..7   (w k-row; +8 for 2nd)
    const int ca = (tid & 31) * 4;    // 0..124 (w col)

    float acc[8][8];
#pragma unroll
    for (int i = 0; i < 8; ++i)
#pragma unroll
        for (int j = 0; j < 8; ++j) acc[i][j] = 0.0f;

    const float* xrow = x + (size_t)(r0 + sr) * DD;
    float4 px0 = *(const float4*)&xrow[sk];
    float4 px1 = *(const float4*)&xrow[sk + 4];
    float4 pw0 = *(const float4*)&Wt0[(size_t)ka * 128 + ca];
    float4 pw1 = *(const float4*)&Wt0[(size_t)(ka + 8) * 128 + ca];

    for (int kc = 0; kc < DD / KC; ++kc) {
        __syncthreads();
        xs[sk + 0][sr] = px0.x; xs[sk + 1][sr] = px0.y;
        xs[sk + 2][sr] = px0.z; xs[sk + 3][sr] = px0.w;
        xs[sk + 4][sr] = px1.x; xs[sk + 5][sr] = px1.y;
        xs[sk + 6][sr] = px1.z; xs[sk + 7][sr] = px1.w;
        *(float4*)&ws[ka][ca]     = pw0;
        *(float4*)&ws[ka + 8][ca] = pw1;
        __syncthreads();

        if (kc + 1 < DD / KC) {
            const int k0 = (kc + 1) * KC;
            px0 = *(const float4*)&xrow[k0 + sk];
            px1 = *(const float4*)&xrow[k0 + sk + 4];
            pw0 = *(const float4*)&Wt0[(size_t)(k0 + ka) * 128 + ca];
            pw1 = *(const float4*)&Wt0[(size_t)(k0 + ka + 8) * 128 + ca];
        }

#pragma unroll
        for (int kk = 0; kk < KC; ++kk) {
            float4 xa = *(const float4*)&xs[kk][rg * 8];
            float4 xb = *(const float4*)&xs[kk][rg * 8 + 4];
            float4 wa = *(const float4*)&ws[kk][cg * 8];
            float4 wb = *(const float4*)&ws[kk][cg * 8 + 4];
            float xr[8] = {xa.x, xa.y, xa.z, xa.w, xb.x, xb.y, xb.z, xb.w};
            float wr[8] = {wa.x, wa.y, wa.z, wa.w, wb.x, wb.y, wb.z, wb.w};
#pragma unroll
            for (int i = 0; i < 8; ++i)
#pragma unroll
                for (int j = 0; j < 8; ++j)
                    acc[i][j] = fmaf(xr[i], wr[j], acc[i][j]);
        }
    }

    // permuted store: gate g -> (lane, slot) of the recurrence layout
#pragma unroll
    for (int j = 0; j < 8; ++j) {
        const int g = cg * 8 + j;
        if (g < G4) {
            const int gm = g % 60;
            const int lane = (gm < HH) ? gm : (32 + gm - HH);
            const int slot = g / 60;
            const float bb = bias0[g];
#pragma unroll
            for (int i = 0; i < 8; ++i) {
                const size_t row = r0 + rg * 8 + i;
                xgp[(row * 64 + lane) * 2 + slot] = acc[i][j] + bb;
            }
        }
    }
}

// ---------------------------------------------------------------------------
// Recurrence: one wave per batch element. 4-deep xg prefetch; h broadcast once.
__global__ __launch_bounds__(64, 1) void lstm_rec(
    const float* __restrict__ xgp,
    const float* __restrict__ Whh0, const float* __restrict__ Wih1,
    const float* __restrict__ Whh1, const float* __restrict__ bih1,
    const float* __restrict__ bhh1, float* __restrict__ h2buf) {
    const int l = threadIdx.x;
    const int b = blockIdx.x;
    const int u = l & 31;
    const int half = l >> 5;
    const bool act = (u < HH);
    const int rlo = half * HH + (act ? u : 0);
    const int rhi = 60 + rlo;

    float w0lo[HH], w0hi[HH], wi1lo[HH], wi1hi[HH], wh1lo[HH], wh1hi[HH];
#pragma unroll
    for (int j = 0; j < HH; ++j) {
        w0lo[j]  = act ? Whh0[rlo * HH + j] : 0.0f;
        w0hi[j]  = act ? Whh0[rhi * HH + j] : 0.0f;
        wi1lo[j] = act ? Wih1[rlo * HH + j] : 0.0f;
        wi1hi[j] = act ? Wih1[rhi * HH + j] : 0.0f;
        wh1lo[j] = act ? Whh1[rlo * HH + j] : 0.0f;
        wh1hi[j] = act ? Whh1[rhi * HH + j] : 0.0f;
    }
    const float b1lo = act ? (bih1[rlo] + bhh1[rlo]) : 0.0f;
    const float b1hi = act ? (bih1[rhi] + bhh1[rhi]) : 0.0f;

    float h1 = 0.0f, c1 = 0.0f, h2 = 0.0f, c2 = 0.0f;
    float hb1[HH], hb2[HH];
#pragma unroll
    for (int j = 0; j < HH; ++j) { hb1[j] = 0.0f; hb2[j] = 0.0f; }

    const float2* xgptr = (const float2*)xgp + (size_t)b * 64 + l;
    float2 xq[4];
#pragma unroll
    for (int p = 0; p < 4; ++p) xq[p] = xgptr[(size_t)p * (BB * 64)];

    for (int t = 0; t < TT; t += 4) {
#pragma unroll
        for (int p = 0; p < 4; ++p) {
            const int tc = t + p;
            const float2 xw = xq[p];
            const int tn = (tc + 4 < TT) ? tc + 4 : TT - 1;
            xq[p] = xgptr[(size_t)tn * (BB * 64)];   // 4-step-deep prefetch

            // ---- L0 gate dot: uses hb1 (SGPR broadcasts from prev step) ----
            float aA = xw.x, aB = 0.0f, bA = xw.y, bB = 0.0f;
#pragma unroll
            for (int j = 0; j < HH; j += 2) {
                aA = fmaf(w0lo[j], hb1[j], aA);
                bA = fmaf(w0hi[j], hb1[j], bA);
                aB = fmaf(w0lo[j + 1], hb1[j + 1], aB);
                bB = fmaf(w0hi[j + 1], hb1[j + 1], bB);
            }
            const float alo = aA + aB, ahi = bA + bB;
            const float plo = __shfl_xor(alo, 32, 64);
            const float phi = __shfl_xor(ahi, 32, 64);

            // ---- overlap: Whh1 . h2 partial (independent of L0) ----
            float zA = b1lo, zB = 0.0f, yA = b1hi, yB = 0.0f;
#pragma unroll
            for (int j = 0; j < HH; j += 2) {
                zA = fmaf(wh1lo[j], hb2[j], zA);
                yA = fmaf(wh1hi[j], hb2[j], yA);
                zB = fmaf(wh1lo[j + 1], hb2[j + 1], zB);
                yB = fmaf(wh1hi[j + 1], hb2[j + 1], yB);
            }

            // ---- L0 activations ----
            float ipre = half ? plo : alo;
            float fpre = half ? alo : plo;
            float gpre = half ? phi : ahi;
            float opre = half ? ahi : phi;
            c1 = fsig(fpre) * c1 + fsig(ipre) * ftan(gpre);
            h1 = fsig(opre) * ftan(c1);

            // ---- broadcast h1 once; reused by wi1 dot AND next step's L0 ----
#pragma unroll
            for (int j = 0; j < HH; ++j) hb1[j] = bcast(h1, j);

            // ---- Wih1 . h1 ----
#pragma unroll
            for (int j = 0; j < HH; j += 2) {
                zA = fmaf(wi1lo[j], hb1[j], zA);
                yA = fmaf(wi1hi[j], hb1[j], yA);
                zB = fmaf(wi1lo[j + 1], hb1[j + 1], zB);
                yB = fmaf(wi1hi[j + 1], hb1[j + 1], yB);
            }
            const float zlo = zA + zB, zhi = yA + yB;
            const float qlo = __shfl_xor(zlo, 32, 64);
            const float qhi = __shfl_xor(zhi, 32, 64);

            ipre = half ? qlo : zlo;
            fpre = half ? zlo : qlo;
            gpre = half ? qhi : zhi;
            opre = half ? zhi : qhi;
            c2 = fsig(fpre) * c2 + fsig(ipre) * ftan(gpre);
            h2 = fsig(opre) * ftan(c2);

            if (l < HH) h2buf[((size_t)tc * BB + b) * 32 + l] = h2;

            // ---- broadcast h2 for next step's Whh1 dot ----
#pragma unroll
            for (int j = 0; j < HH; ++j) hb2[j] = bcast(h2, j);
        }
    }
}

// ---------------------------------------------------------------------------
// Output projection: out[t,b] = h2buf[t,b,:] . Wout + bout
__global__ __launch_bounds__(256) void out_proj(
    const float* __restrict__ h2buf, const float* __restrict__ Wout,
    const float* __restrict__ bout, float* __restrict__ out) {
    __shared__ float wos[32];
    if (threadIdx.x < 32)
        wos[threadIdx.x] = (threadIdx.x < HH) ? Wout[threadIdx.x] : 0.0f;
    __syncthreads();
    const int idx = blockIdx.x * 256 + threadIdx.x;   // 0..65535
    const float4* hp = (const float4*)(h2buf + (size_t)idx * 32);
    float s0 = 0.f, s1 = 0.f;
#pragma unroll
    for (int q = 0; q < 8; ++q) {
        float4 h = hp[q];
        s0 = fmaf(h.x, wos[q * 4 + 0], s0);
        s1 = fmaf(h.y, wos[q * 4 + 1], s1);
        s0 = fmaf(h.z, wos[q * 4 + 2], s0);
        s1 = fmaf(h.w, wos[q * 4 + 3], s1);
    }
    out[idx] = s0 + s1 + bout[0];
}

// ---------------------------------------------------------------------------
extern "C" void kernel_launch(void* const* d_in, const int* in_sizes, int n_in,
                              void* d_out, int out_size, void* d_ws, size_t ws_size,
                              hipStream_t stream) {
    const float* x    = (const float*)d_in[0];
    const float* Wih0 = (const float*)d_in[1];
    const float* Whh0 = (const float*)d_in[2];
    const float* bih0 = (const float*)d_in[3];
    const float* bhh0 = (const float*)d_in[4];
    const float* Wih1 = (const float*)d_in[5];
    const float* Whh1 = (const float*)d_in[6];
    const float* bih1 = (const float*)d_in[7];
    const float* bhh1 = (const float*)d_in[8];
    const float* Wout = (const float*)d_in[9];
    const float* bout = (const float*)d_in[10];
    float* out = (float*)d_out;

    char* ws = (char*)d_ws;
    float* Wt0   = (float*)ws;                             // 512 KB
    float* bias0 = (float*)(ws + 512 * 1024);              // 512 B
    float* xgp   = (float*)(ws + 1024 * 1024);             // 33.55 MB
    float* h2buf = (float*)(ws + 36 * 1024 * 1024);        // 8.39 MB

    prep_kernel<<<512, 256, 0, stream>>>(Wih0, bih0, bhh0, Wt0, bias0);
    gemm_xg<<<512, 256, 0, stream>>>(x, Wt0, bias0, xgp);
    lstm_rec<<<BB, 64, 0, stream>>>(xgp, Whh0, Wih1, Whh1, bih1, bhh1, h2buf);
    out_proj<<<256, 256, 0, stream>>>(h2buf, Wout, bout, out);
}

// Round 4
// 1062.913 us; speedup vs baseline: 2.0262x; 1.1343x over previous
//
#include <hip/hip_runtime.h>
#include <hip/hip_bf16.h>
#include <cstdint>

#define TT 1024
#define BB 64
#define DD 1024
#define HH 30
#define G4 120

typedef __attribute__((ext_vector_type(8))) short short8;
typedef __attribute__((ext_vector_type(4))) float float4v;

// ---------------------------------------------------------------------------
__device__ __forceinline__ float frcp(float x) { return __builtin_amdgcn_rcpf(x); }
__device__ __forceinline__ float fsig(float x) { return frcp(1.0f + __expf(-x)); }
__device__ __forceinline__ float ftan(float x) {
    return 2.0f * frcp(1.0f + __expf(-2.0f * x)) - 1.0f;
}
__device__ __forceinline__ float bcast(float v, int l) {
    return __int_as_float(__builtin_amdgcn_readlane(__float_as_int(v), l));
}
__device__ __forceinline__ unsigned short bf16_rne(float f) {
    unsigned u = __float_as_uint(f);
    return (unsigned short)((u + 0x7FFFu + ((u >> 16) & 1u)) >> 16);
}

// ---------------------------------------------------------------------------
// Prep: pack W_ih0 into MFMA B-fragment order, split bf16 hi/lo.
// B-frag element (nt,kc,lane,j): k = kc*32 + (lane>>4)*8 + j ; n = nt*16 + (lane&15)
__global__ void prep_kernel(const float* __restrict__ Wih0,
                            const float* __restrict__ bih0,
                            const float* __restrict__ bhh0,
                            unsigned short* __restrict__ Bhi,
                            unsigned short* __restrict__ Blo,
                            float* __restrict__ bias0) {
    int idx = blockIdx.x * 256 + threadIdx.x;   // 0..16383
    int l  = idx & 63;
    int kc = (idx >> 6) & 31;
    int nt = idx >> 11;
    int n = nt * 16 + (l & 15);
    int kb = kc * 32 + (l >> 4) * 8;
    size_t o = (size_t)idx * 8;
#pragma unroll
    for (int j = 0; j < 8; ++j) {
        float wv = (n < G4) ? Wih0[(size_t)n * DD + kb + j] : 0.0f;
        unsigned short hi = bf16_rne(wv);
        float fhi = __uint_as_float((unsigned)hi << 16);
        unsigned short lo = bf16_rne(wv - fhi);
        Bhi[o + j] = hi;
        Blo[o + j] = lo;
    }
    if (idx < 128) bias0[idx] = (idx < G4) ? (bih0[idx] + bhh0[idx]) : 0.0f;
}

// ---------------------------------------------------------------------------
// GEMM via split-bf16 MFMA. Block = 4 waves x 32 rows = 128 rows, N=128 cols.
// No LDS: A direct from global (converted in-reg), B pre-packed in L2.
__global__ __launch_bounds__(256) void gemm_xg(
    const float* __restrict__ x, const unsigned short* __restrict__ Bhi,
    const unsigned short* __restrict__ Blo, const float* __restrict__ bias0,
    float* __restrict__ xgp) {
    const int tid = threadIdx.x;
    const int w = tid >> 6;
    const int l = tid & 63;
    const int lm = l & 15, lq = l >> 4;
    const int r0 = blockIdx.x * 128 + w * 32;

    float4v acc[2][8];
#pragma unroll
    for (int mt = 0; mt < 2; ++mt)
#pragma unroll
        for (int nt = 0; nt < 8; ++nt) acc[mt][nt] = (float4v)0.0f;

    const float* aptr[2];
    aptr[0] = x + (size_t)(r0 + lm) * DD + lq * 8;
    aptr[1] = x + (size_t)(r0 + 16 + lm) * DD + lq * 8;

    float4 pa[2][2];
#pragma unroll
    for (int mt = 0; mt < 2; ++mt) {
        pa[mt][0] = *(const float4*)(aptr[mt]);
        pa[mt][1] = *(const float4*)(aptr[mt] + 4);
    }

    for (int kc = 0; kc < 32; ++kc) {
        // convert current A chunk to bf16 hi/lo fragments
        short8 ahi[2], alo[2];
#pragma unroll
        for (int mt = 0; mt < 2; ++mt) {
            float f[8] = {pa[mt][0].x, pa[mt][0].y, pa[mt][0].z, pa[mt][0].w,
                          pa[mt][1].x, pa[mt][1].y, pa[mt][1].z, pa[mt][1].w};
#pragma unroll
            for (int i = 0; i < 8; ++i) {
                unsigned ub = __float_as_uint(f[i]);
                ahi[mt][i] = (short)(ub >> 16);
                float fr = f[i] - __uint_as_float(ub & 0xFFFF0000u);
                alo[mt][i] = (short)(__float_as_uint(fr) >> 16);
            }
        }
        // prefetch next A chunk
        if (kc + 1 < 32) {
            const int ko = (kc + 1) * 32;
#pragma unroll
            for (int mt = 0; mt < 2; ++mt) {
                pa[mt][0] = *(const float4*)(aptr[mt] + ko);
                pa[mt][1] = *(const float4*)(aptr[mt] + ko + 4);
            }
        }
#pragma unroll
        for (int nt = 0; nt < 8; ++nt) {
            const size_t bo = ((size_t)(nt * 32 + kc) * 64 + l) * 8;
            short8 bh = *(const short8*)(Bhi + bo);
            short8 bl = *(const short8*)(Blo + bo);
            acc[0][nt] = __builtin_amdgcn_mfma_f32_16x16x32_bf16(ahi[0], bh, acc[0][nt], 0, 0, 0);
            acc[1][nt] = __builtin_amdgcn_mfma_f32_16x16x32_bf16(ahi[1], bh, acc[1][nt], 0, 0, 0);
            acc[0][nt] = __builtin_amdgcn_mfma_f32_16x16x32_bf16(alo[0], bh, acc[0][nt], 0, 0, 0);
            acc[1][nt] = __builtin_amdgcn_mfma_f32_16x16x32_bf16(alo[1], bh, acc[1][nt], 0, 0, 0);
            acc[0][nt] = __builtin_amdgcn_mfma_f32_16x16x32_bf16(ahi[0], bl, acc[0][nt], 0, 0, 0);
            acc[1][nt] = __builtin_amdgcn_mfma_f32_16x16x32_bf16(ahi[1], bl, acc[1][nt], 0, 0, 0);
        }
    }

    // epilogue: C/D layout col=lane&15, row=quad*4+reg. Permuted store for rec.
#pragma unroll
    for (int nt = 0; nt < 8; ++nt) {
        const int g = nt * 16 + lm;
        if (g < G4) {
            const int gm = g % 60;
            const int lane_t = (gm < HH) ? gm : (32 + gm - HH);
            const int slot = g / 60;
            const float bb = bias0[g];
#pragma unroll
            for (int mt = 0; mt < 2; ++mt)
#pragma unroll
                for (int i = 0; i < 4; ++i) {
                    const size_t row = r0 + mt * 16 + lq * 4 + i;
                    xgp[(row * 64 + lane_t) * 2 + slot] = acc[mt][nt][i] + bb;
                }
        }
    }
}

// ---------------------------------------------------------------------------
// Recurrence: 2 waves per block (one batch element). Wave0 = layer 0 + Wih1.h1
// partial; wave1 (1-step skew) = + Whh1.h2, activations, h2 store.
__global__ __launch_bounds__(128, 1) void lstm_rec(
    const float* __restrict__ xgp, const float* __restrict__ Whh0,
    const float* __restrict__ Wih1, const float* __restrict__ Whh1,
    const float* __restrict__ bih1, const float* __restrict__ bhh1,
    float* __restrict__ h2buf) {
    const int tid = threadIdx.x;
    const int wv = tid >> 6;
    const int l = tid & 63;
    const int b = blockIdx.x;
    const int u = l & 31;
    const int half = l >> 5;
    const bool al = (u < HH);
    const int rlo = half * HH + (al ? u : 0);
    const int rhi = 60 + rlo;

    __shared__ float2 pg[2][64];   // partial layer-1 gates ring

    float wa[HH], wb[HH], wc[HH], wd[HH];
    float b1lo = 0.f, b1hi = 0.f;
    if (wv == 0) {
#pragma unroll
        for (int j = 0; j < HH; ++j) {
            wa[j] = al ? Whh0[rlo * HH + j] : 0.f;
            wb[j] = al ? Whh0[rhi * HH + j] : 0.f;
            wc[j] = al ? Wih1[rlo * HH + j] : 0.f;
            wd[j] = al ? Wih1[rhi * HH + j] : 0.f;
        }
        b1lo = al ? (bih1[rlo] + bhh1[rlo]) : 0.f;
        b1hi = al ? (bih1[rhi] + bhh1[rhi]) : 0.f;
    } else {
#pragma unroll
        for (int j = 0; j < HH; ++j) {
            wa[j] = al ? Whh1[rlo * HH + j] : 0.f;
            wb[j] = al ? Whh1[rhi * HH + j] : 0.f;
            wc[j] = 0.f; wd[j] = 0.f;
        }
    }

    float hstate = 0.f, cstate = 0.f;
    float hb[HH];
#pragma unroll
    for (int j = 0; j < HH; ++j) hb[j] = 0.f;

    const float2* xgptr = (const float2*)xgp + (size_t)b * 64 + l;
    float2 xq[4];
    if (wv == 0) {
#pragma unroll
        for (int p = 0; p < 4; ++p) xq[p] = xgptr[(size_t)p * (BB * 64)];
    }

    for (int t = 0; t <= TT; ++t) {
        if (wv == 0) {
            if (t < TT) {
                float2 xw = xq[t & 3];
                const int tn = (t + 4 < TT) ? t + 4 : TT - 1;
                xq[t & 3] = xgptr[(size_t)tn * (BB * 64)];

                // layer-0 gate dot (hb = h1 broadcasts from prev step)
                float aA = xw.x, aB = 0.f, cA = xw.y, cB = 0.f;
#pragma unroll
                for (int j = 0; j < HH; j += 2) {
                    aA = fmaf(wa[j], hb[j], aA);
                    cA = fmaf(wb[j], hb[j], cA);
                    aB = fmaf(wa[j + 1], hb[j + 1], aB);
                    cB = fmaf(wb[j + 1], hb[j + 1], cB);
                }
                float alo = aA + aB, ahi = cA + cB;
                float plo = __shfl_xor(alo, 32, 64);
                float phi = __shfl_xor(ahi, 32, 64);
                float ipre = half ? plo : alo;
                float fpre = half ? alo : plo;
                float gpre = half ? phi : ahi;
                float opre = half ? ahi : phi;
                cstate = fsig(fpre) * cstate + fsig(ipre) * ftan(gpre);
                hstate = fsig(opre) * ftan(cstate);
#pragma unroll
                for (int j = 0; j < HH; ++j) hb[j] = bcast(hstate, j);

                // layer-1 input partial: bias1 + Wih1 . h1(t)
                float zA = b1lo, zB = 0.f, yA = b1hi, yB = 0.f;
#pragma unroll
                for (int j = 0; j < HH; j += 2) {
                    zA = fmaf(wc[j], hb[j], zA);
                    yA = fmaf(wd[j], hb[j], yA);
                    zB = fmaf(wc[j + 1], hb[j + 1], zB);
                    yB = fmaf(wd[j + 1], hb[j + 1], yB);
                }
                pg[t & 1][l] = make_float2(zA + zB, yA + yB);
            }
        } else {
            if (t > 0) {
                const int s = t - 1;
                float2 part = pg[s & 1][l];
                float zA = part.x, zB = 0.f, yA = part.y, yB = 0.f;
#pragma unroll
                for (int j = 0; j < HH; j += 2) {
                    zA = fmaf(wa[j], hb[j], zA);       // Whh1 . h2(s-1)
                    yA = fmaf(wb[j], hb[j], yA);
                    zB = fmaf(wa[j + 1], hb[j + 1], zB);
                    yB = fmaf(wb[j + 1], hb[j + 1], yB);
                }
                float zlo = zA + zB, zhi = yA + yB;
                float qlo = __shfl_xor(zlo, 32, 64);
                float qhi = __shfl_xor(zhi, 32, 64);
                float ipre = half ? qlo : zlo;
                float fpre = half ? zlo : qlo;
                float gpre = half ? qhi : zhi;
                float opre = half ? zhi : qhi;
                cstate = fsig(fpre) * cstate + fsig(ipre) * ftan(gpre);
                hstate = fsig(opre) * ftan(cstate);
#pragma unroll
                for (int j = 0; j < HH; ++j) hb[j] = bcast(hstate, j);
                if (l < HH) h2buf[((size_t)s * BB + b) * 32 + l] = hstate;
            }
        }
        __syncthreads();
    }
}

// ---------------------------------------------------------------------------
// Output projection: out[t,b] = h2buf[t,b,:] . Wout + bout
__global__ __launch_bounds__(256) void out_proj(
    const float* __restrict__ h2buf, const float* __restrict__ Wout,
    const float* __restrict__ bout, float* __restrict__ out) {
    __shared__ float wos[32];
    if (threadIdx.x < 32)
        wos[threadIdx.x] = (threadIdx.x < HH) ? Wout[threadIdx.x] : 0.0f;
    __syncthreads();
    const int idx = blockIdx.x * 256 + threadIdx.x;   // 0..65535
    const float4* hp = (const float4*)(h2buf + (size_t)idx * 32);
    float s0 = 0.f, s1 = 0.f;
#pragma unroll
    for (int q = 0; q < 8; ++q) {
        float4 h = hp[q];
        s0 = fmaf(h.x, wos[q * 4 + 0], s0);
        s1 = fmaf(h.y, wos[q * 4 + 1], s1);
        s0 = fmaf(h.z, wos[q * 4 + 2], s0);
        s1 = fmaf(h.w, wos[q * 4 + 3], s1);
    }
    out[idx] = s0 + s1 + bout[0];
}

// ---------------------------------------------------------------------------
extern "C" void kernel_launch(void* const* d_in, const int* in_sizes, int n_in,
                              void* d_out, int out_size, void* d_ws, size_t ws_size,
                              hipStream_t stream) {
    const float* x    = (const float*)d_in[0];
    const float* Wih0 = (const float*)d_in[1];
    const float* Whh0 = (const float*)d_in[2];
    const float* bih0 = (const float*)d_in[3];
    const float* bhh0 = (const float*)d_in[4];
    const float* Wih1 = (const float*)d_in[5];
    const float* Whh1 = (const float*)d_in[6];
    const float* bih1 = (const float*)d_in[7];
    const float* bhh1 = (const float*)d_in[8];
    const float* Wout = (const float*)d_in[9];
    const float* bout = (const float*)d_in[10];
    float* out = (float*)d_out;

    char* ws = (char*)d_ws;
    unsigned short* Bhi = (unsigned short*)ws;                 // 256 KB
    unsigned short* Blo = (unsigned short*)(ws + 262144);      // 256 KB
    float* bias0 = (float*)(ws + 524288);                      // 512 B
    float* xgp   = (float*)(ws + 1024 * 1024);                 // 33.55 MB
    float* h2buf = (float*)(ws + 36 * 1024 * 1024);            // 8.39 MB

    prep_kernel<<<64, 256, 0, stream>>>(Wih0, bih0, bhh0, Bhi, Blo, bias0);
    gemm_xg<<<512, 256, 0, stream>>>(x, Bhi, Blo, bias0, xgp);
    lstm_rec<<<BB, 128, 0, stream>>>(xgp, Whh0, Wih1, Whh1, bih1, bhh1, h2buf);
    out_proj<<<256, 256, 0, stream>>>(h2buf, Wout, bout, out);
}